// Round 1
// baseline (426.160 us; speedup 1.0000x reference)
//
#include <hip/hip_runtime.h>

#define BB 32
#define PP 32768
#define CC 81
#define TPB 128   // threads per block == priors per tile in K1

// ws layout:
//   [0..7]    double loss_l accumulator
//   [8..15]   double loss_c accumulator (pos-CE sum + mined-negative sum)
//   [16..143] int num_pos[32]
//   [512.. ]  float mine[B*P]  (4 MB)

__device__ __forceinline__ float sl1f(float d) {
    float ad = fabsf(d);
    return ad < 1.f ? 0.5f * d * d : ad - 0.5f;
}

__global__ __launch_bounds__(TPB) void ce_loc_kernel(
    const float* __restrict__ conf, const int* __restrict__ labels,
    const float* __restrict__ locd, const float* __restrict__ loct,
    float* __restrict__ mine, double* __restrict__ accs, int* __restrict__ num_pos)
{
    __shared__ float tile[TPB * CC];       // 41472 B
    __shared__ float wsum[2], wce[2];
    __shared__ int   wpc[2];

    const int t = threadIdx.x;
    const size_t gp0 = (size_t)blockIdx.x * TPB;

    // ---- coalesced global -> LDS copy: 128*81 floats = 2592 float4 ----
    // tile start offset = blockIdx*128*81*4 bytes, divisible by 16 -> aligned.
    const float4* s4 = (const float4*)(conf + gp0 * CC);
    float4* d4 = (float4*)tile;
#pragma unroll
    for (int i = 0; i < 20; ++i) d4[t + i * TPB] = s4[t + i * TPB];
    if (t < 32) d4[2560 + t] = s4[2560 + t];
    __syncthreads();

    // ---- per-thread CE over its prior's 81 classes (LDS stride 81: gcd(81,32)=1, conflict-free) ----
    const float* row = tile + t * CC;
    float m = row[0];
#pragma unroll
    for (int c = 1; c < CC; ++c) m = fmaxf(m, row[c]);
    float s = 0.f;
#pragma unroll
    for (int c = 0; c < CC; ++c) s += __expf(row[c] - m);

    const size_t gp = gp0 + t;
    const int lab = labels[gp];
    const float ce = m + __logf(s) - row[lab];
    const bool pos = lab > 0;
    // mining key value: positives zeroed (matches reference loss_mine), clamp for
    // uint-monotone float ordering in the radix select
    mine[gp] = pos ? 0.f : fmaxf(ce, 0.f);

    // ---- localization smooth-L1 (float4 loads, 16B aligned) ----
    const float4 a = ((const float4*)locd)[gp];
    const float4 b = ((const float4*)loct)[gp];
    float ll = 0.f;
    if (pos) ll = sl1f(a.x - b.x) + sl1f(a.y - b.y) + sl1f(a.z - b.z) + sl1f(a.w - b.w);
    float pce = pos ? ce : 0.f;
    int pc = pos ? 1 : 0;

    // ---- block reduce (wave64 shuffle, then 2-wave combine) ----
#pragma unroll
    for (int off = 32; off; off >>= 1) {
        ll  += __shfl_down(ll, off);
        pce += __shfl_down(pce, off);
        pc  += __shfl_down(pc, off);
    }
    const int w = t >> 6;
    if ((t & 63) == 0) { wsum[w] = ll; wce[w] = pce; wpc[w] = pc; }
    __syncthreads();
    if (t == 0) {
        atomicAdd(&accs[0], (double)(wsum[0] + wsum[1]));
        atomicAdd(&accs[1], (double)(wce[0] + wce[1]));      // positive CE always selected
        atomicAdd(&num_pos[blockIdx.x >> 8], wpc[0] + wpc[1]); // 256 blocks per row
    }
}

// Per-row top-k sum via radix select on float bits (keys >= 0).
// k = min(3*num_pos, P-1). Selected-sum = sum_{key>v} m  +  (k - count(key>v)) * v,
// which is exactly the reference's stable-argsort selection sum (ties share a value).
__global__ __launch_bounds__(1024) void mine_kernel(
    const float* __restrict__ mine, const int* __restrict__ num_pos,
    double* __restrict__ loss_c_acc)
{
    const int b = blockIdx.x;
    const float* mr = mine + (size_t)b * PP;
    const int t = threadIdx.x;
    __shared__ unsigned hist[256];
    __shared__ unsigned sh_prefix;
    __shared__ int sh_remaining;
    __shared__ float sred[16];

    const int np = num_pos[b];
    const int k = min(3 * np, PP - 1);
    if (k <= 0) return;

    unsigned prefix = 0;
    int remaining = k;
    for (int lvl = 0; lvl < 4; ++lvl) {
        const int shift = 24 - lvl * 8;
        if (t < 256) hist[t] = 0;
        __syncthreads();
        for (int p = t; p < PP; p += 1024) {
            const unsigned key = __float_as_uint(mr[p]);
            const bool cand = (lvl == 0) || ((key >> (shift + 8)) == prefix);
            if (cand) atomicAdd(&hist[(key >> shift) & 255u], 1u);
        }
        __syncthreads();
        if (t == 0) {
            unsigned c = 0;
            int j = 255;
            for (; j > 0; --j) {                 // find bucket holding the k-th largest
                const unsigned h = hist[j];
                if (c + h >= (unsigned)remaining) break;
                c += h;
            }
            sh_prefix = (prefix << 8) | (unsigned)j;
            sh_remaining = remaining - (int)c;
        }
        __syncthreads();
        prefix = sh_prefix;
        remaining = sh_remaining;
        __syncthreads();
    }

    const unsigned vkey = prefix;
    const float v = __uint_as_float(vkey);
    float sgt = 0.f;
    for (int p = t; p < PP; p += 1024) {
        const float mv = mr[p];
        if (__float_as_uint(mv) > vkey) sgt += mv;
    }
#pragma unroll
    for (int off = 32; off; off >>= 1) sgt += __shfl_down(sgt, off);
    if ((t & 63) == 0) sred[t >> 6] = sgt;
    __syncthreads();
    if (t == 0) {
        float tot = 0.f;
#pragma unroll
        for (int w2 = 0; w2 < 16; ++w2) tot += sred[w2];
        tot += (float)remaining * v;             // boundary-value ties
        atomicAdd(loss_c_acc, (double)tot);
    }
}

__global__ void finalize_kernel(const double* __restrict__ accs,
                                const int* __restrict__ num_pos,
                                float* __restrict__ out)
{
    if (threadIdx.x == 0 && blockIdx.x == 0) {
        int N = 0;
#pragma unroll
        for (int b = 0; b < BB; ++b) N += num_pos[b];
        const float fN = (float)N;
        out[0] = (float)accs[0] / fN;   // LOC_WEIGHT = 1
        out[1] = (float)accs[1] / fN;   // CONF_WEIGHT = 1
    }
}

extern "C" void kernel_launch(void* const* d_in, const int* in_sizes, int n_in,
                              void* d_out, int out_size, void* d_ws, size_t ws_size,
                              hipStream_t stream)
{
    const float* locd   = (const float*)d_in[0];
    const float* conf   = (const float*)d_in[1];
    const float* loct   = (const float*)d_in[2];
    const int*   labels = (const int*)d_in[3];
    float* out = (float*)d_out;

    char* ws = (char*)d_ws;
    double* accs   = (double*)ws;
    int*    numpos = (int*)(ws + 16);
    float*  mine   = (float*)(ws + 512);

    hipMemsetAsync(d_ws, 0, 512, stream);   // zero accumulators every call (graph-safe)

    ce_loc_kernel<<<(BB * PP) / TPB, TPB, 0, stream>>>(conf, labels, locd, loct,
                                                       mine, accs, numpos);
    mine_kernel<<<BB, 1024, 0, stream>>>(mine, numpos, &accs[1]);
    finalize_kernel<<<1, 64, 0, stream>>>(accs, numpos, out);
}